// Round 3
// baseline (333.491 us; speedup 1.0000x reference)
//
#include <hip/hip_runtime.h>
#include <hip/hip_bf16.h>

typedef float f32x4 __attribute__((ext_vector_type(4)));

#define B_  8192
#define H_  128
#define NW  1106    // G + 3*W
#define NC  640     // gates gemm output cols (r,u,s,gi_n,gh_n)
#define KK  256

static const size_t N4TOT = (size_t)NW * NW * H_ / 4;   // 39,143,552 float4s

// copy-slice sizes (float4 units)
#define SL1 6000000UL
#define SL2 4000000UL

#define K1_CPB 1024
#define K2_CB  2048
#define K2_CPB 1024
#define K3_CPB 2048

__device__ __forceinline__ float sigmf(float x) { return 1.0f / (1.0f + expf(-x)); }

__device__ __forceinline__ void copy_span(const f32x4* __restrict__ src,
                                          f32x4* __restrict__ dst,
                                          size_t lo, size_t hi,
                                          size_t ctid, size_t cthreads) {
    for (size_t i = lo + ctid; i < hi; i += cthreads) {
        f32x4 v = __builtin_nontemporal_load(src + i);
        __builtin_nontemporal_store(v, dst + i);
    }
}

// ---------------------------------------------------------------------------
// K1: gates GEMM directly from xf/hx/w_ih/w_hh (no Z, no Wbig).
// Cbuf[b][j]: j in [0,128)=r, [128,256)=u, [256,384)=s, [384,512)=gi_n,
// [512,640)=gh_n.  Strip s covers j=[128s,128s+128):
//   strip 0,1: wrow=j      both halves (ih for k<128, hh for k>=128)
//   strip 2:   wrow=j+128  both halves
//   strip 3:   wrow=j-128  ih only  (k in [0,128))
//   strip 4:   wrow=j-256  hh only  (k in [128,256))
// Extra blocks: first 32 do winner atomicMax; all do copy slice.
// ---------------------------------------------------------------------------
__global__ __launch_bounds__(256) void k1_gates(
    const float* __restrict__ xf, const float* __restrict__ hx,
    const float* __restrict__ w_ih, const float* __restrict__ w_hh,
    float* __restrict__ Cbuf, const int* __restrict__ gidx, int* __restrict__ winner,
    const f32x4* __restrict__ src, f32x4* __restrict__ dst, size_t lo, size_t hi) {
    __shared__ float As[64][36];
    __shared__ float Ws[32][132];
    int bid = blockIdx.x, tid = threadIdx.x;
    if (bid >= 640) {
        int rel = bid - 640;
        if (rel < 32) {
            int b = rel * 256 + tid;
            int gx = gidx[2 * b] + 2, gy = gidx[2 * b + 1] + 2;
            atomicMax(&winner[gx * NW + gy], b);
        }
        size_t ctid = (size_t)rel * 256 + tid;
        copy_span(src, dst, lo, hi, ctid, (size_t)(gridDim.x - 640) * 256);
        return;
    }
    int bx = bid & 127;          // m block
    int strip = bid >> 7;        // 0..4
    size_t m0 = (size_t)bx * 64;
    int n0 = strip * 128;
    // weight row base for this strip's 128 cols
    int wbase = (strip == 0) ? 0 : (strip == 1) ? 128 : (strip == 2) ? 384 : 256;
    int kstart = (strip == 4) ? 128 : 0;
    int kend   = (strip == 3) ? 128 : 256;

    int tn = tid & 15, tm = tid >> 4;
    float acc[4][8];
#pragma unroll
    for (int i = 0; i < 4; ++i)
#pragma unroll
        for (int j = 0; j < 8; ++j) acc[i][j] = 0.0f;

    for (int k0 = kstart; k0 < kend; k0 += 32) {
        const float* asrc = (k0 < 128) ? xf : hx;
        const float* wsrc = (strip == 3) ? w_ih
                          : (strip == 4) ? w_hh
                          : (k0 < 128 ? w_ih : w_hh);
        int koff = k0 & 127;
        __syncthreads();
#pragma unroll
        for (int p = 0; p < 2; ++p) {        // A tile 64x32 from xf|hx
            int f = tid + 256 * p; int r = f >> 3, cq = f & 7;
            float4 v = *(const float4*)(asrc + (m0 + r) * 128 + koff + 4 * cq);
            *(float4*)(&As[r][4 * cq]) = v;
        }
#pragma unroll
        for (int p = 0; p < 4; ++p) {        // W tile 128x32 transposed
            int f = tid + 256 * p; int c = f >> 3, cq = f & 7;
            float4 v = *(const float4*)(wsrc + (size_t)(wbase + c) * 128 + koff + 4 * cq);
            Ws[4 * cq + 0][c] = v.x; Ws[4 * cq + 1][c] = v.y;
            Ws[4 * cq + 2][c] = v.z; Ws[4 * cq + 3][c] = v.w;
        }
        __syncthreads();
#pragma unroll
        for (int kk = 0; kk < 32; ++kk) {
            float4 w0 = *(const float4*)(&Ws[kk][4 * tn]);
            float4 w1 = *(const float4*)(&Ws[kk][64 + 4 * tn]);
#pragma unroll
            for (int i = 0; i < 4; ++i) {
                float a = As[4 * tm + i][kk];
                acc[i][0] += a * w0.x; acc[i][1] += a * w0.y;
                acc[i][2] += a * w0.z; acc[i][3] += a * w0.w;
                acc[i][4] += a * w1.x; acc[i][5] += a * w1.y;
                acc[i][6] += a * w1.z; acc[i][7] += a * w1.w;
            }
        }
    }
#pragma unroll
    for (int i = 0; i < 4; ++i) {
        size_t row = m0 + 4 * tm + i;
        float4 v0 = make_float4(acc[i][0], acc[i][1], acc[i][2], acc[i][3]);
        float4 v1 = make_float4(acc[i][4], acc[i][5], acc[i][6], acc[i][7]);
        *(float4*)(Cbuf + row * NC + n0 + 4 * tn) = v0;
        *(float4*)(Cbuf + row * NC + n0 + 64 + 4 * tn) = v1;
    }
}

// ---------------------------------------------------------------------------
// K2: gates + attention. 256-thread blocks, one wave per batch item.
// ---------------------------------------------------------------------------
__global__ __launch_bounds__(256) void k2_attn(
    const float* __restrict__ C, const float* __restrict__ memory,
    const int* __restrict__ gidx, const float* __restrict__ b_ih,
    const float* __restrict__ b_hh, float* __restrict__ mixq,
    float* __restrict__ ug, float* __restrict__ sg,
    const f32x4* __restrict__ src, f32x4* __restrict__ dst, size_t lo, size_t hi) {
    int bid = blockIdx.x, tid = threadIdx.x;
    if (bid >= K2_CB) {
        size_t ctid = (size_t)(bid - K2_CB) * 256 + tid;
        copy_span(src, dst, lo, hi, ctid, (size_t)(gridDim.x - K2_CB) * 256);
        return;
    }
    int b = bid * 4 + (tid >> 6);
    int t = tid & 63;
    int t1 = t + 64;
    const float* Crow = C + (size_t)b * NC;
    float r0 = sigmf(Crow[t]        + b_ih[t]        + b_hh[t]);
    float r1 = sigmf(Crow[t1]       + b_ih[t1]       + b_hh[t1]);
    float u0 = sigmf(Crow[128 + t]  + b_ih[128 + t]  + b_hh[128 + t]);
    float u1 = sigmf(Crow[128 + t1] + b_ih[128 + t1] + b_hh[128 + t1]);
    float s0 = sigmf(Crow[256 + t]  + b_ih[384 + t]  + b_hh[384 + t]);
    float s1 = sigmf(Crow[256 + t1] + b_ih[384 + t1] + b_hh[384 + t1]);
    float n0 = tanhf(Crow[384 + t]  + b_ih[256 + t]  + r0 * (Crow[512 + t]  + b_hh[256 + t]));
    float n1 = tanhf(Crow[384 + t1] + b_ih[256 + t1] + r1 * (Crow[512 + t1] + b_hh[256 + t1]));

    int gx = gidx[2 * b] + 2, gy = gidx[2 * b + 1] + 2;
    const float* base = memory + ((size_t)gx * NW + gy) * H_ + t;
    float cs0[25], cs1[25];
#pragma unroll
    for (int l = 0; l < 25; ++l) {
        int dx = l / 5 - 2, dy = l % 5 - 2;
        const float* row = base + ((long)dx * NW + dy) * H_;
        cs0[l] = row[0];
        cs1[l] = row[64];
    }
    float sc[25];
#pragma unroll
    for (int l = 0; l < 25; ++l) {
        float p = n0 * cs0[l] + n1 * cs1[l];
#pragma unroll
        for (int w = 1; w < 64; w <<= 1) p += __shfl_xor(p, w, 64);
        sc[l] = p;
    }
    float mx = sc[0];
#pragma unroll
    for (int l = 1; l < 25; ++l) mx = fmaxf(mx, sc[l]);
    float den = 0.0f, mix0 = 0.0f, mix1 = 0.0f;
#pragma unroll
    for (int l = 0; l < 25; ++l) {
        float e = expf(sc[l] - mx);
        den += e;
        mix0 += e * cs0[l];
        mix1 += e * cs1[l];
    }
    float inv = 1.0f / den;
    mix0 *= inv; mix1 *= inv;

    float* mq = mixq + (size_t)b * 256;
    mq[t] = mix0; mq[t1] = mix1; mq[128 + t] = n0; mq[128 + t1] = n1;
    ug[(size_t)b * H_ + t] = u0; ug[(size_t)b * H_ + t1] = u1;
    sg[(size_t)b * H_ + t] = s0; sg[(size_t)b * H_ + t1] = s1;
}

// ---------------------------------------------------------------------------
// K3: fused out-GEMM (AC = mixq @ w_out^T) + GRU combine + scatter + copy rest
// 128 compute blocks own 64 complete rows each (BN = 128 = H).
// Copy blocks skip winner cells (compute blocks write those).
// ---------------------------------------------------------------------------
__global__ __launch_bounds__(256) void k3_final(
    const float* __restrict__ mixq, const float* __restrict__ w_out,
    const float* __restrict__ b_out, const float* __restrict__ sg,
    const float* __restrict__ ug, const float* __restrict__ hx,
    const float* __restrict__ memory, const int* __restrict__ gidx,
    const int* __restrict__ winner, float* __restrict__ hyy,
    float* __restrict__ newmem,
    const f32x4* __restrict__ src, f32x4* __restrict__ dst, size_t lo, size_t hi) {
    __shared__ float As[64][36];
    __shared__ float Ws[32][132];
    int bid = blockIdx.x, tid = threadIdx.x;
    if (bid >= 128) {
        size_t ctid = (size_t)(bid - 128) * 256 + tid;
        size_t nthr = (size_t)(gridDim.x - 128) * 256;
        for (size_t i = lo + ctid; i < hi; i += nthr) {
            if (winner[i >> 5] < 0) {
                f32x4 v = __builtin_nontemporal_load(src + i);
                __builtin_nontemporal_store(v, dst + i);
            }
        }
        return;
    }
    size_t m0 = (size_t)bid * 64;
    int tn = tid & 15, tm = tid >> 4;
    float acc[4][8];
#pragma unroll
    for (int i = 0; i < 4; ++i)
#pragma unroll
        for (int j = 0; j < 8; ++j) acc[i][j] = 0.0f;

    for (int k0 = 0; k0 < KK; k0 += 32) {
        __syncthreads();
#pragma unroll
        for (int p = 0; p < 2; ++p) {        // A tile 64x32 from mixq
            int f = tid + 256 * p; int r = f >> 3, cq = f & 7;
            float4 v = *(const float4*)(mixq + (m0 + r) * KK + k0 + 4 * cq);
            *(float4*)(&As[r][4 * cq]) = v;
        }
#pragma unroll
        for (int p = 0; p < 4; ++p) {        // w_out tile 128x32 transposed
            int f = tid + 256 * p; int c = f >> 3, cq = f & 7;
            float4 v = *(const float4*)(w_out + (size_t)c * KK + k0 + 4 * cq);
            Ws[4 * cq + 0][c] = v.x; Ws[4 * cq + 1][c] = v.y;
            Ws[4 * cq + 2][c] = v.z; Ws[4 * cq + 3][c] = v.w;
        }
        __syncthreads();
#pragma unroll
        for (int kk = 0; kk < 32; ++kk) {
            float4 w0 = *(const float4*)(&Ws[kk][4 * tn]);
            float4 w1 = *(const float4*)(&Ws[kk][64 + 4 * tn]);
#pragma unroll
            for (int i = 0; i < 4; ++i) {
                float a = As[4 * tm + i][kk];
                acc[i][0] += a * w0.x; acc[i][1] += a * w0.y;
                acc[i][2] += a * w0.z; acc[i][3] += a * w0.w;
                acc[i][4] += a * w1.x; acc[i][5] += a * w1.y;
                acc[i][6] += a * w1.z; acc[i][7] += a * w1.w;
            }
        }
    }
    // epilogue: per (row, col) GRU combine + scatter
#pragma unroll
    for (int i = 0; i < 4; ++i) {
        size_t row = m0 + 4 * tm + i;
        int gx = gidx[2 * row] + 2, gy = gidx[2 * row + 1] + 2;
        size_t cell = (size_t)gx * NW + gy;
        bool win = (winner[cell] == (int)row);
#pragma unroll
        for (int half = 0; half < 2; ++half) {
#pragma unroll
            for (int j = 0; j < 4; ++j) {
                int col = half * 64 + 4 * tn + j;
                float a = acc[i][half * 4 + j];
                float atten = tanhf(a + b_out[col]);
                float s = sg[row * H_ + col];
                float u = ug[row * H_ + col];
                float q = mixq[row * 256 + 128 + col];
                float curr = q + s * atten;
                float hy = curr + u * (hx[row * H_ + col] - curr);
                hyy[row * H_ + col] = hy;
                if (win) {
                    float m = memory[cell * H_ + col];
                    newmem[cell * H_ + col] = s * m + (1.0f - s) * hy;
                }
            }
        }
    }
}

// serial-fallback bulk copy
__global__ void copy_kernel(const f32x4* __restrict__ src, f32x4* __restrict__ dst, size_t n4) {
    size_t stride = (size_t)gridDim.x * blockDim.x;
    for (size_t i = (size_t)blockIdx.x * blockDim.x + threadIdx.x; i < n4; i += stride) {
        f32x4 v = __builtin_nontemporal_load(src + i);
        __builtin_nontemporal_store(v, dst + i);
    }
}

extern "C" void kernel_launch(void* const* d_in, const int* in_sizes, int n_in,
                              void* d_out, int out_size, void* d_ws, size_t ws_size,
                              hipStream_t stream) {
    const float* xf     = (const float*)d_in[0];
    const float* hx     = (const float*)d_in[1];
    const int*   gidx   = (const int*)d_in[2];
    const float* memory = (const float*)d_in[3];
    const float* w_ih   = (const float*)d_in[4];
    const float* w_hh   = (const float*)d_in[5];
    const float* b_ih   = (const float*)d_in[6];
    const float* b_hh   = (const float*)d_in[7];
    const float* w_out  = (const float*)d_in[8];
    const float* b_out  = (const float*)d_in[9];

    float* out    = (float*)d_out;
    float* hyy    = out;
    float* newmem = out + (size_t)B_ * H_;
    const f32x4* src4 = (const f32x4*)memory;
    f32x4*       dst4 = (f32x4*)newmem;

    // Persistent scratch: mixq, ug, sg, winner
    float* wsf    = (float*)d_ws;
    float* mixq   = wsf;                           // B*256
    float* ug     = mixq + (size_t)B_ * 256;       // B*128
    float* sg     = ug + (size_t)B_ * H_;          // B*128
    int*   winner = (int*)(sg + (size_t)B_ * H_);  // NW*NW ints
    char*  pers_end = (char*)(winner + (size_t)NW * NW);
    size_t pers_bytes = (size_t)(pers_end - (char*)d_ws);

    size_t CF = (size_t)B_ * NC;                   // Cbuf floats
    bool distributed = (ws_size >= pers_bytes + CF * sizeof(float));
    float* Cbuf = distributed ? (float*)pers_end : newmem;

    hipMemsetAsync(winner, 0xFF, (size_t)NW * NW * sizeof(int), stream);

    if (distributed) {
        size_t a1 = SL1, b1 = a1 + SL2;
        k1_gates<<<640 + K1_CPB, 256, 0, stream>>>(
            xf, hx, w_ih, w_hh, Cbuf, gidx, winner, src4, dst4, 0, a1);
        k2_attn<<<K2_CB + K2_CPB, 256, 0, stream>>>(
            Cbuf, memory, gidx, b_ih, b_hh, mixq, ug, sg, src4, dst4, a1, b1);
        k3_final<<<128 + K3_CPB, 256, 0, stream>>>(
            mixq, w_out, b_out, sg, ug, hx, memory, gidx, winner, hyy, newmem,
            src4, dst4, b1, N4TOT);
    } else {
        // serial fallback: Cbuf staged in not-yet-copied newmem region
        k1_gates<<<640 + 32, 256, 0, stream>>>(
            xf, hx, w_ih, w_hh, Cbuf, gidx, winner, src4, dst4, 0, 0);
        k2_attn<<<K2_CB, 256, 0, stream>>>(
            Cbuf, memory, gidx, b_ih, b_hh, mixq, ug, sg, src4, dst4, 0, 0);
        copy_kernel<<<2048, 256, 0, stream>>>(src4, dst4, N4TOT);
        k3_final<<<128 + 32, 256, 0, stream>>>(
            mixq, w_out, b_out, sg, ug, hx, memory, gidx, winner, hyy, newmem,
            src4, dst4, 0, 0);
    }
}

// Round 4
// 319.130 us; speedup vs baseline: 1.0450x; 1.0450x over previous
//
#include <hip/hip_runtime.h>
#include <hip/hip_bf16.h>

typedef float f32x4 __attribute__((ext_vector_type(4)));

#define B_  8192
#define H_  128
#define NW  1106    // G + 3*W
#define NC  640     // gates gemm output cols (r,u,s,gi_n,gh_n)
#define KK  256

static const size_t N4TOT = (size_t)NW * NW * H_ / 4;   // 39,143,552 float4s

// copy-slice boundaries (float4 units)
#define S0_ 4000000UL
#define S1_ 10000000UL
#define S2_ 14500000UL

#define K0_BLKS 1024
#define K1_CPB  1024
#define K2_CPB  4096
#define K3_CPB  2048

__device__ __forceinline__ float sigmf(float x) { return 1.0f / (1.0f + expf(-x)); }

__device__ __forceinline__ void copy_span(const f32x4* __restrict__ src,
                                          f32x4* __restrict__ dst,
                                          size_t lo, size_t hi,
                                          size_t ctid, size_t cthreads) {
    for (size_t i = lo + ctid; i < hi; i += cthreads) {
        f32x4 v = __builtin_nontemporal_load(src + i);
        __builtin_nontemporal_store(v, dst + i);
    }
}

// ---------------------------------------------------------------------------
// K0: winner = -1 (full-BW grid-stride, NOT a memset node) + copy slice
// ---------------------------------------------------------------------------
__global__ __launch_bounds__(256) void k0_init(
    int* __restrict__ winner,
    const f32x4* __restrict__ src, f32x4* __restrict__ dst, size_t lo, size_t hi) {
    size_t gt = (size_t)blockIdx.x * 256 + threadIdx.x;
    size_t nthr = (size_t)gridDim.x * 256;
    for (size_t i = gt; i < (size_t)NW * NW; i += nthr) winner[i] = -1;
    copy_span(src, dst, lo, hi, gt, nthr);
}

// ---------------------------------------------------------------------------
// K1: gates GEMM directly from xf/hx/w_ih/w_hh (no Z, no Wbig).
// Cbuf[b][j]: [0,128)=r, [128,256)=u, [256,384)=s, [384,512)=gi_n, [512,640)=gh_n
//   strip 0,1: wrow=j      both k-halves (ih k<128, hh k>=128)
//   strip 2:   wrow=j+128  both halves
//   strip 3:   wrow=j-128  ih only (k<128)
//   strip 4:   wrow=j-256  hh only (k>=128)
// Extra blocks: first 32 do winner atomicMax; all do copy slice.
// ---------------------------------------------------------------------------
__global__ __launch_bounds__(256) void k1_gates(
    const float* __restrict__ xf, const float* __restrict__ hx,
    const float* __restrict__ w_ih, const float* __restrict__ w_hh,
    float* __restrict__ Cbuf, const int* __restrict__ gidx, int* __restrict__ winner,
    const f32x4* __restrict__ src, f32x4* __restrict__ dst, size_t lo, size_t hi) {
    __shared__ float As[64][36];
    __shared__ float Ws[32][132];
    int bid = blockIdx.x, tid = threadIdx.x;
    if (bid >= 640) {
        int rel = bid - 640;
        if (rel < 32) {
            int b = rel * 256 + tid;
            int gx = gidx[2 * b] + 2, gy = gidx[2 * b + 1] + 2;
            atomicMax(&winner[gx * NW + gy], b);
        }
        size_t ctid = (size_t)rel * 256 + tid;
        copy_span(src, dst, lo, hi, ctid, (size_t)(gridDim.x - 640) * 256);
        return;
    }
    int bx = bid & 127;          // m block
    int strip = bid >> 7;        // 0..4
    size_t m0 = (size_t)bx * 64;
    int n0 = strip * 128;
    int wbase = (strip == 0) ? 0 : (strip == 1) ? 128 : (strip == 2) ? 384 : 256;
    int kstart = (strip == 4) ? 128 : 0;
    int kend   = (strip == 3) ? 128 : 256;

    int tn = tid & 15, tm = tid >> 4;
    float acc[4][8];
#pragma unroll
    for (int i = 0; i < 4; ++i)
#pragma unroll
        for (int j = 0; j < 8; ++j) acc[i][j] = 0.0f;

    for (int k0 = kstart; k0 < kend; k0 += 32) {
        const float* asrc = (k0 < 128) ? xf : hx;
        const float* wsrc = (strip == 3) ? w_ih
                          : (strip == 4) ? w_hh
                          : (k0 < 128 ? w_ih : w_hh);
        int koff = k0 & 127;
        __syncthreads();
#pragma unroll
        for (int p = 0; p < 2; ++p) {        // A tile 64x32 from xf|hx
            int f = tid + 256 * p; int r = f >> 3, cq = f & 7;
            float4 v = *(const float4*)(asrc + (m0 + r) * 128 + koff + 4 * cq);
            *(float4*)(&As[r][4 * cq]) = v;
        }
#pragma unroll
        for (int p = 0; p < 4; ++p) {        // W tile 128x32 transposed
            int f = tid + 256 * p; int c = f >> 3, cq = f & 7;
            float4 v = *(const float4*)(wsrc + (size_t)(wbase + c) * 128 + koff + 4 * cq);
            Ws[4 * cq + 0][c] = v.x; Ws[4 * cq + 1][c] = v.y;
            Ws[4 * cq + 2][c] = v.z; Ws[4 * cq + 3][c] = v.w;
        }
        __syncthreads();
#pragma unroll
        for (int kk = 0; kk < 32; ++kk) {
            float4 w0 = *(const float4*)(&Ws[kk][4 * tn]);
            float4 w1 = *(const float4*)(&Ws[kk][64 + 4 * tn]);
#pragma unroll
            for (int i = 0; i < 4; ++i) {
                float a = As[4 * tm + i][kk];
                acc[i][0] += a * w0.x; acc[i][1] += a * w0.y;
                acc[i][2] += a * w0.z; acc[i][3] += a * w0.w;
                acc[i][4] += a * w1.x; acc[i][5] += a * w1.y;
                acc[i][6] += a * w1.z; acc[i][7] += a * w1.w;
            }
        }
    }
#pragma unroll
    for (int i = 0; i < 4; ++i) {
        size_t row = m0 + 4 * tm + i;
        float4 v0 = make_float4(acc[i][0], acc[i][1], acc[i][2], acc[i][3]);
        float4 v1 = make_float4(acc[i][4], acc[i][5], acc[i][6], acc[i][7]);
        *(float4*)(Cbuf + row * NC + n0 + 4 * tn) = v0;
        *(float4*)(Cbuf + row * NC + n0 + 64 + 4 * tn) = v1;
    }
}

// ---------------------------------------------------------------------------
// K2: gates + attention. One 64-thread wave per batch item (round-2 shape).
// ---------------------------------------------------------------------------
__global__ __launch_bounds__(64) void k2_attn(
    const float* __restrict__ C, const float* __restrict__ memory,
    const int* __restrict__ gidx, const float* __restrict__ b_ih,
    const float* __restrict__ b_hh, float* __restrict__ mixq,
    float* __restrict__ ug, float* __restrict__ sg,
    const f32x4* __restrict__ src, f32x4* __restrict__ dst, size_t lo, size_t hi) {
    int bid = blockIdx.x;
    int t = threadIdx.x;
    if (bid >= B_) {
        size_t ctid = (size_t)(bid - B_) * 64 + t;
        copy_span(src, dst, lo, hi, ctid, (size_t)(gridDim.x - B_) * 64);
        return;
    }
    int b = bid;
    int t1 = t + 64;
    const float* Crow = C + (size_t)b * NC;
    float r0 = sigmf(Crow[t]        + b_ih[t]        + b_hh[t]);
    float r1 = sigmf(Crow[t1]       + b_ih[t1]       + b_hh[t1]);
    float u0 = sigmf(Crow[128 + t]  + b_ih[128 + t]  + b_hh[128 + t]);
    float u1 = sigmf(Crow[128 + t1] + b_ih[128 + t1] + b_hh[128 + t1]);
    float s0 = sigmf(Crow[256 + t]  + b_ih[384 + t]  + b_hh[384 + t]);
    float s1 = sigmf(Crow[256 + t1] + b_ih[384 + t1] + b_hh[384 + t1]);
    float n0 = tanhf(Crow[384 + t]  + b_ih[256 + t]  + r0 * (Crow[512 + t]  + b_hh[256 + t]));
    float n1 = tanhf(Crow[384 + t1] + b_ih[256 + t1] + r1 * (Crow[512 + t1] + b_hh[256 + t1]));

    int gx = gidx[2 * b] + 2, gy = gidx[2 * b + 1] + 2;
    const float* base = memory + ((size_t)gx * NW + gy) * H_ + t;
    float cs0[25], cs1[25];
#pragma unroll
    for (int l = 0; l < 25; ++l) {
        int dx = l / 5 - 2, dy = l % 5 - 2;
        const float* row = base + ((long)dx * NW + dy) * H_;
        cs0[l] = row[0];
        cs1[l] = row[64];
    }
    float sc[25];
#pragma unroll
    for (int l = 0; l < 25; ++l) {
        float p = n0 * cs0[l] + n1 * cs1[l];
#pragma unroll
        for (int w = 1; w < 64; w <<= 1) p += __shfl_xor(p, w, 64);
        sc[l] = p;
    }
    float mx = sc[0];
#pragma unroll
    for (int l = 1; l < 25; ++l) mx = fmaxf(mx, sc[l]);
    float den = 0.0f, mix0 = 0.0f, mix1 = 0.0f;
#pragma unroll
    for (int l = 0; l < 25; ++l) {
        float e = expf(sc[l] - mx);
        den += e;
        mix0 += e * cs0[l];
        mix1 += e * cs1[l];
    }
    float inv = 1.0f / den;
    mix0 *= inv; mix1 *= inv;

    float* mq = mixq + (size_t)b * 256;
    mq[t] = mix0; mq[t1] = mix1; mq[128 + t] = n0; mq[128 + t1] = n1;
    ug[(size_t)b * H_ + t] = u0; ug[(size_t)b * H_ + t1] = u1;
    sg[(size_t)b * H_ + t] = s0; sg[(size_t)b * H_ + t1] = s1;
}

// ---------------------------------------------------------------------------
// K3: fused out-GEMM (AC = mixq @ w_out^T) + GRU combine + scatter + copy rest
// 128 compute blocks own 64 complete rows each (BN = 128 = H).
// Copy blocks skip winner cells (compute blocks write those).
// ---------------------------------------------------------------------------
__global__ __launch_bounds__(256) void k3_final(
    const float* __restrict__ mixq, const float* __restrict__ w_out,
    const float* __restrict__ b_out, const float* __restrict__ sg,
    const float* __restrict__ ug, const float* __restrict__ hx,
    const float* __restrict__ memory, const int* __restrict__ gidx,
    const int* __restrict__ winner, float* __restrict__ hyy,
    float* __restrict__ newmem,
    const f32x4* __restrict__ src, f32x4* __restrict__ dst, size_t lo, size_t hi) {
    __shared__ float As[64][36];
    __shared__ float Ws[32][132];
    int bid = blockIdx.x, tid = threadIdx.x;
    if (bid >= 128) {
        size_t ctid = (size_t)(bid - 128) * 256 + tid;
        size_t nthr = (size_t)(gridDim.x - 128) * 256;
        for (size_t i = lo + ctid; i < hi; i += nthr) {
            if (winner[i >> 5] < 0) {
                f32x4 v = __builtin_nontemporal_load(src + i);
                __builtin_nontemporal_store(v, dst + i);
            }
        }
        return;
    }
    size_t m0 = (size_t)bid * 64;
    int tn = tid & 15, tm = tid >> 4;
    float acc[4][8];
#pragma unroll
    for (int i = 0; i < 4; ++i)
#pragma unroll
        for (int j = 0; j < 8; ++j) acc[i][j] = 0.0f;

    for (int k0 = 0; k0 < KK; k0 += 32) {
        __syncthreads();
#pragma unroll
        for (int p = 0; p < 2; ++p) {        // A tile 64x32 from mixq
            int f = tid + 256 * p; int r = f >> 3, cq = f & 7;
            float4 v = *(const float4*)(mixq + (m0 + r) * KK + k0 + 4 * cq);
            *(float4*)(&As[r][4 * cq]) = v;
        }
#pragma unroll
        for (int p = 0; p < 4; ++p) {        // w_out tile 128x32 transposed
            int f = tid + 256 * p; int c = f >> 3, cq = f & 7;
            float4 v = *(const float4*)(w_out + (size_t)c * KK + k0 + 4 * cq);
            Ws[4 * cq + 0][c] = v.x; Ws[4 * cq + 1][c] = v.y;
            Ws[4 * cq + 2][c] = v.z; Ws[4 * cq + 3][c] = v.w;
        }
        __syncthreads();
#pragma unroll
        for (int kk = 0; kk < 32; ++kk) {
            float4 w0 = *(const float4*)(&Ws[kk][4 * tn]);
            float4 w1 = *(const float4*)(&Ws[kk][64 + 4 * tn]);
#pragma unroll
            for (int i = 0; i < 4; ++i) {
                float a = As[4 * tm + i][kk];
                acc[i][0] += a * w0.x; acc[i][1] += a * w0.y;
                acc[i][2] += a * w0.z; acc[i][3] += a * w0.w;
                acc[i][4] += a * w1.x; acc[i][5] += a * w1.y;
                acc[i][6] += a * w1.z; acc[i][7] += a * w1.w;
            }
        }
    }
#pragma unroll
    for (int i = 0; i < 4; ++i) {
        size_t row = m0 + 4 * tm + i;
        int gx = gidx[2 * row] + 2, gy = gidx[2 * row + 1] + 2;
        size_t cell = (size_t)gx * NW + gy;
        bool win = (winner[cell] == (int)row);
#pragma unroll
        for (int half = 0; half < 2; ++half) {
#pragma unroll
            for (int j = 0; j < 4; ++j) {
                int col = half * 64 + 4 * tn + j;
                float a = acc[i][half * 4 + j];
                float atten = tanhf(a + b_out[col]);
                float s = sg[row * H_ + col];
                float u = ug[row * H_ + col];
                float q = mixq[row * 256 + 128 + col];
                float curr = q + s * atten;
                float hy = curr + u * (hx[row * H_ + col] - curr);
                hyy[row * H_ + col] = hy;
                if (win) {
                    float m = memory[cell * H_ + col];
                    newmem[cell * H_ + col] = s * m + (1.0f - s) * hy;
                }
            }
        }
    }
}

// serial-fallback bulk copy
__global__ void copy_kernel(const f32x4* __restrict__ src, f32x4* __restrict__ dst, size_t n4) {
    size_t stride = (size_t)gridDim.x * blockDim.x;
    for (size_t i = (size_t)blockIdx.x * blockDim.x + threadIdx.x; i < n4; i += stride) {
        f32x4 v = __builtin_nontemporal_load(src + i);
        __builtin_nontemporal_store(v, dst + i);
    }
}

extern "C" void kernel_launch(void* const* d_in, const int* in_sizes, int n_in,
                              void* d_out, int out_size, void* d_ws, size_t ws_size,
                              hipStream_t stream) {
    const float* xf     = (const float*)d_in[0];
    const float* hx     = (const float*)d_in[1];
    const int*   gidx   = (const int*)d_in[2];
    const float* memory = (const float*)d_in[3];
    const float* w_ih   = (const float*)d_in[4];
    const float* w_hh   = (const float*)d_in[5];
    const float* b_ih   = (const float*)d_in[6];
    const float* b_hh   = (const float*)d_in[7];
    const float* w_out  = (const float*)d_in[8];
    const float* b_out  = (const float*)d_in[9];

    float* out    = (float*)d_out;
    float* hyy    = out;
    float* newmem = out + (size_t)B_ * H_;
    const f32x4* src4 = (const f32x4*)memory;
    f32x4*       dst4 = (f32x4*)newmem;

    // Persistent scratch: mixq, ug, sg, winner
    float* wsf    = (float*)d_ws;
    float* mixq   = wsf;                           // B*256
    float* ug     = mixq + (size_t)B_ * 256;       // B*128
    float* sg     = ug + (size_t)B_ * H_;          // B*128
    int*   winner = (int*)(sg + (size_t)B_ * H_);  // NW*NW ints
    char*  pers_end = (char*)(winner + (size_t)NW * NW);
    size_t pers_bytes = (size_t)(pers_end - (char*)d_ws);

    size_t CF = (size_t)B_ * NC;                   // Cbuf floats
    bool distributed = (ws_size >= pers_bytes + CF * sizeof(float));
    float* Cbuf = distributed ? (float*)pers_end : newmem;

    if (distributed) {
        k0_init<<<K0_BLKS, 256, 0, stream>>>(winner, src4, dst4, 0, S0_);
        k1_gates<<<640 + K1_CPB, 256, 0, stream>>>(
            xf, hx, w_ih, w_hh, Cbuf, gidx, winner, src4, dst4, S0_, S1_);
        k2_attn<<<B_ + K2_CPB, 64, 0, stream>>>(
            Cbuf, memory, gidx, b_ih, b_hh, mixq, ug, sg, src4, dst4, S1_, S2_);
        k3_final<<<128 + K3_CPB, 256, 0, stream>>>(
            mixq, w_out, b_out, sg, ug, hx, memory, gidx, winner, hyy, newmem,
            src4, dst4, S2_, N4TOT);
    } else {
        // serial fallback: Cbuf staged in not-yet-copied newmem region
        k0_init<<<K0_BLKS, 256, 0, stream>>>(winner, src4, dst4, 0, 0);
        k1_gates<<<640 + 32, 256, 0, stream>>>(
            xf, hx, w_ih, w_hh, Cbuf, gidx, winner, src4, dst4, 0, 0);
        k2_attn<<<B_, 64, 0, stream>>>(
            Cbuf, memory, gidx, b_ih, b_hh, mixq, ug, sg, src4, dst4, 0, 0);
        copy_kernel<<<2048, 256, 0, stream>>>(src4, dst4, N4TOT);
        k3_final<<<128 + 32, 256, 0, stream>>>(
            mixq, w_out, b_out, sg, ug, hx, memory, gidx, winner, hyy, newmem,
            src4, dst4, 0, 0);
    }
}

// Round 5
// 296.514 us; speedup vs baseline: 1.1247x; 1.0763x over previous
//
#include <hip/hip_runtime.h>
#include <hip/hip_bf16.h>

typedef float f32x4 __attribute__((ext_vector_type(4)));

#define B_  8192
#define H_  128
#define NW  1106    // G + 3*W
#define NC  640     // wide gemm output cols (r,u,s,gi_n,gh_n)
#define KK  256     // K for both GEMMs

static const size_t N4TOT = (size_t)NW * NW * H_ / 4;   // 39,143,552 float4s

// copy-slice sizes (float4 units) per phase — round-2 proven constants
#define SL_A 2000000UL
#define SL_B 6000000UL
#define SL_C 5000000UL
#define SL_D 2000000UL

#define PREP_CB  512     // prep compute blocks
#define PREP_CPB 768     // prep copy blocks
#define GEMM_CPB 1024
#define ATTN_CPB 4096
#define FIN_BLKS 2048

__device__ __forceinline__ float sigmf(float x) { return 1.0f / (1.0f + expf(-x)); }

__device__ __forceinline__ void copy_span(const f32x4* __restrict__ src,
                                          f32x4* __restrict__ dst,
                                          size_t lo, size_t hi,
                                          size_t ctid, size_t cthreads) {
    for (size_t i = lo + ctid; i < hi; i += cthreads) {
        f32x4 v = __builtin_nontemporal_load(src + i);
        __builtin_nontemporal_store(v, dst + i);
    }
}

// ---------------------------------------------------------------------------
// Prep: Z = [x|hx] (B x 256), Wbig (640 x 256), winner = -1; + copy slice A
// ---------------------------------------------------------------------------
__global__ __launch_bounds__(256) void prep_kernel(
    const float* __restrict__ xf, const float* __restrict__ hx,
    const float* __restrict__ w_ih, const float* __restrict__ w_hh,
    float* __restrict__ Z, float* __restrict__ Wbig, int* __restrict__ winner,
    const f32x4* __restrict__ src, f32x4* __restrict__ dst, size_t lo, size_t hi) {
    int bid = blockIdx.x, tid = threadIdx.x;
    if (bid >= PREP_CB) {
        size_t ctid = (size_t)(bid - PREP_CB) * 256 + tid;
        copy_span(src, dst, lo, hi, ctid, (size_t)(gridDim.x - PREP_CB) * 256);
        return;
    }
    size_t stride = (size_t)PREP_CB * 256;
    size_t id0 = (size_t)bid * 256 + tid;
    for (size_t i = id0; i < (size_t)B_ * 256; i += stride) {
        size_t b = i >> 8; int c = (int)(i & 255);
        Z[i] = (c < 128) ? xf[b * 128 + c] : hx[b * 128 + (c - 128)];
    }
    for (size_t i = id0; i < (size_t)NC * 256; i += stride) {
        int j = (int)(i >> 8); int k = (int)(i & 255);
        float v;
        if (j < 256) {
            v = (k < 128) ? w_ih[j * 128 + k] : w_hh[j * 128 + (k - 128)];
        } else if (j < 384) {
            int r = 384 + (j - 256);
            v = (k < 128) ? w_ih[r * 128 + k] : w_hh[r * 128 + (k - 128)];
        } else if (j < 512) {
            int r = 256 + (j - 384);
            v = (k < 128) ? w_ih[r * 128 + k] : 0.0f;
        } else {
            int r = 256 + (j - 512);
            v = (k < 128) ? 0.0f : w_hh[r * 128 + (k - 128)];
        }
        Wbig[i] = v;
    }
    for (size_t i = id0; i < (size_t)NW * NW; i += stride) winner[i] = -1;
}

// ---------------------------------------------------------------------------
// Tiled f32 GEMM (+ optional atomicMax side-work + copy slice in extra blocks)
// ---------------------------------------------------------------------------
__global__ __launch_bounds__(256) void gemm_abt(
    const float* __restrict__ A, const float* __restrict__ Bw,
    float* __restrict__ Cc, int ldc, int nx, int nxny,
    const int* __restrict__ gidx, int* __restrict__ winner,
    const f32x4* __restrict__ src, f32x4* __restrict__ dst, size_t lo, size_t hi) {
    __shared__ float As[64][36];
    __shared__ float Ws[32][132];
    int bid = blockIdx.x, tid = threadIdx.x;
    if (bid >= nxny) {
        int rel = bid - nxny;
        if (gidx != nullptr && rel < 32) {   // winner atomics (winner init'd in prep)
            int b = rel * 256 + tid;
            int gx = gidx[2 * b] + 2, gy = gidx[2 * b + 1] + 2;
            atomicMax(&winner[gx * NW + gy], b);
        }
        size_t ctid = (size_t)rel * 256 + tid;
        copy_span(src, dst, lo, hi, ctid, (size_t)(gridDim.x - nxny) * 256);
        return;
    }
    int bx = bid % nx, by = bid / nx;
    int tn = tid & 15, tm = tid >> 4;
    size_t m0 = (size_t)bx * 64;
    int n0 = by * 128;
    float acc[4][8];
#pragma unroll
    for (int i = 0; i < 4; ++i)
#pragma unroll
        for (int j = 0; j < 8; ++j) acc[i][j] = 0.0f;

    for (int k0 = 0; k0 < KK; k0 += 32) {
        __syncthreads();
#pragma unroll
        for (int p = 0; p < 2; ++p) {
            int f = tid + 256 * p; int r = f >> 3, cq = f & 7;
            float4 v = *(const float4*)(A + (m0 + r) * KK + (k0 + 4 * cq));
            *(float4*)(&As[r][4 * cq]) = v;
        }
#pragma unroll
        for (int p = 0; p < 4; ++p) {
            int f = tid + 256 * p; int c = f >> 3, cq = f & 7;
            float4 v = *(const float4*)(Bw + (size_t)(n0 + c) * KK + (k0 + 4 * cq));
            Ws[4 * cq + 0][c] = v.x; Ws[4 * cq + 1][c] = v.y;
            Ws[4 * cq + 2][c] = v.z; Ws[4 * cq + 3][c] = v.w;
        }
        __syncthreads();
#pragma unroll
        for (int kk = 0; kk < 32; ++kk) {
            float4 w0 = *(const float4*)(&Ws[kk][4 * tn]);
            float4 w1 = *(const float4*)(&Ws[kk][64 + 4 * tn]);
#pragma unroll
            for (int i = 0; i < 4; ++i) {
                float a = As[4 * tm + i][kk];
                acc[i][0] += a * w0.x; acc[i][1] += a * w0.y;
                acc[i][2] += a * w0.z; acc[i][3] += a * w0.w;
                acc[i][4] += a * w1.x; acc[i][5] += a * w1.y;
                acc[i][6] += a * w1.z; acc[i][7] += a * w1.w;
            }
        }
    }
#pragma unroll
    for (int i = 0; i < 4; ++i) {
        size_t row = m0 + 4 * tm + i;
        float4 v0 = make_float4(acc[i][0], acc[i][1], acc[i][2], acc[i][3]);
        float4 v1 = make_float4(acc[i][4], acc[i][5], acc[i][6], acc[i][7]);
        *(float4*)(Cc + row * ldc + n0 + 4 * tn) = v0;
        *(float4*)(Cc + row * ldc + n0 + 64 + 4 * tn) = v1;
    }
}

// ---------------------------------------------------------------------------
// Attention: one wave per b; + copy slice in extra blocks
// ---------------------------------------------------------------------------
__global__ __launch_bounds__(64) void attn_kernel(
    const float* __restrict__ C, const float* __restrict__ memory,
    const int* __restrict__ gidx, const float* __restrict__ b_ih,
    const float* __restrict__ b_hh, float* __restrict__ mixq,
    float* __restrict__ ug, float* __restrict__ sg,
    const f32x4* __restrict__ src, f32x4* __restrict__ dst, size_t lo, size_t hi) {
    int bid = blockIdx.x;
    int t = threadIdx.x;
    if (bid >= B_) {
        size_t ctid = (size_t)(bid - B_) * 64 + t;
        copy_span(src, dst, lo, hi, ctid, (size_t)(gridDim.x - B_) * 64);
        return;
    }
    int b = bid;
    int t1 = t + 64;
    const float* Crow = C + (size_t)b * NC;
    float r0 = sigmf(Crow[t]        + b_ih[t]        + b_hh[t]);
    float r1 = sigmf(Crow[t1]       + b_ih[t1]       + b_hh[t1]);
    float u0 = sigmf(Crow[128 + t]  + b_ih[128 + t]  + b_hh[128 + t]);
    float u1 = sigmf(Crow[128 + t1] + b_ih[128 + t1] + b_hh[128 + t1]);
    float s0 = sigmf(Crow[256 + t]  + b_ih[384 + t]  + b_hh[384 + t]);
    float s1 = sigmf(Crow[256 + t1] + b_ih[384 + t1] + b_hh[384 + t1]);
    float n0 = tanhf(Crow[384 + t]  + b_ih[256 + t]  + r0 * (Crow[512 + t]  + b_hh[256 + t]));
    float n1 = tanhf(Crow[384 + t1] + b_ih[256 + t1] + r1 * (Crow[512 + t1] + b_hh[256 + t1]));

    int gx = gidx[2 * b] + 2, gy = gidx[2 * b + 1] + 2;
    const float* base = memory + ((size_t)gx * NW + gy) * H_ + t;
    float cs0[25], cs1[25];
#pragma unroll
    for (int l = 0; l < 25; ++l) {
        int dx = l / 5 - 2, dy = l % 5 - 2;
        const float* row = base + ((long)dx * NW + dy) * H_;
        cs0[l] = row[0];
        cs1[l] = row[64];
    }
    float sc[25];
#pragma unroll
    for (int l = 0; l < 25; ++l) {
        float p = n0 * cs0[l] + n1 * cs1[l];
#pragma unroll
        for (int w = 1; w < 64; w <<= 1) p += __shfl_xor(p, w, 64);
        sc[l] = p;
    }
    float mx = sc[0];
#pragma unroll
    for (int l = 1; l < 25; ++l) mx = fmaxf(mx, sc[l]);
    float den = 0.0f, mix0 = 0.0f, mix1 = 0.0f;
#pragma unroll
    for (int l = 0; l < 25; ++l) {
        float e = expf(sc[l] - mx);
        den += e;
        mix0 += e * cs0[l];
        mix1 += e * cs1[l];
    }
    float inv = 1.0f / den;
    mix0 *= inv; mix1 *= inv;

    float* mq = mixq + (size_t)b * 256;
    mq[t] = mix0; mq[t1] = mix1; mq[128 + t] = n0; mq[128 + t1] = n1;
    ug[(size_t)b * H_ + t] = u0; ug[(size_t)b * H_ + t1] = u1;
    sg[(size_t)b * H_ + t] = s0; sg[(size_t)b * H_ + t1] = s1;
}

// ---------------------------------------------------------------------------
// Pure bulk copy (serial-fallback path only)
// ---------------------------------------------------------------------------
__global__ void copy_kernel(const f32x4* __restrict__ src, f32x4* __restrict__ dst, size_t n4) {
    size_t stride = (size_t)gridDim.x * blockDim.x;
    for (size_t i = (size_t)blockIdx.x * blockDim.x + threadIdx.x; i < n4; i += stride) {
        f32x4 v = __builtin_nontemporal_load(src + i);
        __builtin_nontemporal_store(v, dst + i);
    }
}

// ---------------------------------------------------------------------------
// Final: hyy + stage scatter rows in upd; UNCONDITIONAL copy slice (no checks)
// ---------------------------------------------------------------------------
__global__ __launch_bounds__(256) void final_kernel(
    const float* __restrict__ AC, const float* __restrict__ b_out,
    const float* __restrict__ sg, const float* __restrict__ ug,
    const float* __restrict__ mixq, const float* __restrict__ hx,
    const float* __restrict__ memory, const int* __restrict__ gidx,
    float* __restrict__ hyy, float* __restrict__ upd,
    const f32x4* __restrict__ src, f32x4* __restrict__ dst, size_t lo, size_t hi) {
    size_t gt = (size_t)blockIdx.x * blockDim.x + threadIdx.x;
    size_t nthr = (size_t)gridDim.x * blockDim.x;
    for (size_t i = gt; i < (size_t)B_ * H_; i += nthr) {
        int b = (int)(i >> 7), t = (int)(i & 127);
        float atten = tanhf(AC[i] + b_out[t]);
        float s = sg[i], u = ug[i];
        float q = mixq[(size_t)b * 256 + 128 + t];
        float curr = q + s * atten;
        float hy = curr + u * (hx[i] - curr);
        hyy[i] = hy;
        int gx = gidx[2 * b] + 2, gy = gidx[2 * b + 1] + 2;
        size_t cell = (size_t)gx * NW + gy;
        float m = memory[cell * H_ + t];
        upd[i] = s * m + (1.0f - s) * hy;
    }
    copy_span(src, dst, lo, hi, gt, nthr);
}

// ---------------------------------------------------------------------------
// Scatter: overwrite winner rows of newmem with staged upd rows (~4 MB max)
// thread task = (b, quarter-row of 8 float4s)
// ---------------------------------------------------------------------------
__global__ __launch_bounds__(256) void scatter_kernel(
    const int* __restrict__ gidx, const int* __restrict__ winner,
    const float* __restrict__ upd, float* __restrict__ newmem) {
    int task = blockIdx.x * 256 + threadIdx.x;   // 0 .. B_*4-1
    int b = task >> 2, q = task & 3;
    int gx = gidx[2 * b] + 2, gy = gidx[2 * b + 1] + 2;
    size_t cell = (size_t)gx * NW + gy;
    if (winner[cell] != b) return;
    const f32x4* s = (const f32x4*)(upd + (size_t)b * H_) + q * 8;
    f32x4* d = (f32x4*)(newmem + cell * H_) + q * 8;
#pragma unroll
    for (int j = 0; j < 8; ++j) d[j] = s[j];
}

extern "C" void kernel_launch(void* const* d_in, const int* in_sizes, int n_in,
                              void* d_out, int out_size, void* d_ws, size_t ws_size,
                              hipStream_t stream) {
    const float* xf     = (const float*)d_in[0];
    const float* hx     = (const float*)d_in[1];
    const int*   gidx   = (const int*)d_in[2];
    const float* memory = (const float*)d_in[3];
    const float* w_ih   = (const float*)d_in[4];
    const float* w_hh   = (const float*)d_in[5];
    const float* b_ih   = (const float*)d_in[6];
    const float* b_hh   = (const float*)d_in[7];
    const float* w_out  = (const float*)d_in[8];
    const float* b_out  = (const float*)d_in[9];

    float* out    = (float*)d_out;
    float* hyy    = out;
    float* newmem = out + (size_t)B_ * H_;
    const f32x4* src4 = (const f32x4*)memory;
    f32x4*       dst4 = (f32x4*)newmem;

    // Persistent scratch: mixq, ug, sg, AC, upd, winner
    float* wsf    = (float*)d_ws;
    float* mixq   = wsf;                           // B*256
    float* ug     = mixq + (size_t)B_ * 256;       // B*128
    float* sg     = ug + (size_t)B_ * H_;          // B*128
    float* AC     = sg + (size_t)B_ * H_;          // B*128
    float* upd    = AC + (size_t)B_ * H_;          // B*128
    int*   winner = (int*)(upd + (size_t)B_ * H_); // NW*NW ints
    char*  pers_end = (char*)(winner + (size_t)NW * NW);
    size_t pers_bytes = (size_t)(pers_end - (char*)d_ws);

    size_t ZF = (size_t)B_ * 256, CF = (size_t)B_ * NC, WBF = (size_t)NC * 256;
    size_t trans_bytes = (ZF + CF + WBF) * sizeof(float);
    bool distributed = (ws_size >= pers_bytes + trans_bytes);
    float* trans = distributed ? (float*)pers_end : newmem;
    float* Z    = trans;
    float* Cbuf = Z + ZF;
    float* Wbig = Cbuf + CF;

    if (distributed) {
        size_t a1 = SL_A, b1 = a1 + SL_B, c1 = b1 + SL_C, d1 = c1 + SL_D;
        prep_kernel<<<PREP_CB + PREP_CPB, 256, 0, stream>>>(
            xf, hx, w_ih, w_hh, Z, Wbig, winner, src4, dst4, 0, a1);
        gemm_abt<<<640 + GEMM_CPB, 256, 0, stream>>>(
            Z, Wbig, Cbuf, NC, 128, 640, gidx, winner, src4, dst4, a1, b1);
        attn_kernel<<<B_ + ATTN_CPB, 64, 0, stream>>>(
            Cbuf, memory, gidx, b_ih, b_hh, mixq, ug, sg, src4, dst4, b1, c1);
        gemm_abt<<<128 + GEMM_CPB, 256, 0, stream>>>(
            mixq, w_out, AC, H_, 128, 128, nullptr, winner, src4, dst4, c1, d1);
        final_kernel<<<FIN_BLKS, 256, 0, stream>>>(
            AC, b_out, sg, ug, mixq, hx, memory, gidx, hyy, upd,
            src4, dst4, d1, N4TOT);
        scatter_kernel<<<B_ * 4 / 256, 256, 0, stream>>>(gidx, winner, upd, newmem);
    } else {
        // serial fallback: transients staged in not-yet-copied newmem region
        prep_kernel<<<PREP_CB, 256, 0, stream>>>(
            xf, hx, w_ih, w_hh, Z, Wbig, winner, src4, dst4, 0, 0);
        gemm_abt<<<640 + 32, 256, 0, stream>>>(
            Z, Wbig, Cbuf, NC, 128, 640, gidx, winner, src4, dst4, 0, 0);
        attn_kernel<<<B_, 64, 0, stream>>>(
            Cbuf, memory, gidx, b_ih, b_hh, mixq, ug, sg, src4, dst4, 0, 0);
        gemm_abt<<<128, 256, 0, stream>>>(
            mixq, w_out, AC, H_, 128, 128, nullptr, winner, src4, dst4, 0, 0);
        copy_kernel<<<2048, 256, 0, stream>>>(src4, dst4, N4TOT);
        final_kernel<<<FIN_BLKS, 256, 0, stream>>>(
            AC, b_out, sg, ug, mixq, hx, memory, gidx, hyy, upd,
            src4, dst4, 0, 0);
        scatter_kernel<<<B_ * 4 / 256, 256, 0, stream>>>(gidx, winner, upd, newmem);
    }
}

// Round 6
// 286.009 us; speedup vs baseline: 1.1660x; 1.0367x over previous
//
#include <hip/hip_runtime.h>
#include <hip/hip_bf16.h>

typedef float f32x4 __attribute__((ext_vector_type(4)));

#define B_  8192
#define H_  128
#define NW  1106    // G + 3*W
#define NC  640     // wide gemm output cols (r,u,s,gi_n,gh_n)
#define KK  256     // K for both GEMMs

static const size_t N4TOT = (size_t)NW * NW * H_ / 4;   // 39,143,552 float4s

// copy-slice sizes (float4 units) per phase
#define SL_A 1500000UL
#define SL_B 7000000UL
#define SL_C 5000000UL
#define SL_D 2500000UL

#define PREP_CB  256
#define PREP_CPB 1024
#define GEMM_CPB 1024
#define ATTN_CPB 4096
#define FIN_BLKS 2048

__device__ __forceinline__ float sigmf(float x) { return 1.0f / (1.0f + expf(-x)); }

__device__ __forceinline__ void copy_span(const f32x4* __restrict__ src,
                                          f32x4* __restrict__ dst,
                                          size_t lo, size_t hi,
                                          size_t ctid, size_t cthreads) {
    for (size_t i = lo + ctid; i < hi; i += cthreads) {
        f32x4 v = __builtin_nontemporal_load(src + i);
        __builtin_nontemporal_store(v, dst + i);
    }
}

// ---------------------------------------------------------------------------
// Prep: Wbig (640 x 256), winner = -1; + copy slice A.  (Z eliminated.)
// Wbig rows: [0,128)=r (wih|whh), [128,256)=u, [256,384)=s (w rows 384..512),
// [384,512)=gi_n (wih_n|0), [512,640)=gh_n (0|whh_n)
// ---------------------------------------------------------------------------
__global__ __launch_bounds__(256) void prep_kernel(
    const float* __restrict__ w_ih, const float* __restrict__ w_hh,
    float* __restrict__ Wbig, int* __restrict__ winner,
    const f32x4* __restrict__ src, f32x4* __restrict__ dst, size_t lo, size_t hi) {
    int bid = blockIdx.x, tid = threadIdx.x;
    if (bid >= PREP_CB) {
        size_t ctid = (size_t)(bid - PREP_CB) * 256 + tid;
        copy_span(src, dst, lo, hi, ctid, (size_t)(gridDim.x - PREP_CB) * 256);
        return;
    }
    size_t stride = (size_t)PREP_CB * 256;
    size_t id0 = (size_t)bid * 256 + tid;
    for (size_t i = id0; i < (size_t)NC * 256; i += stride) {
        int j = (int)(i >> 8); int k = (int)(i & 255);
        float v;
        if (j < 256) {
            v = (k < 128) ? w_ih[j * 128 + k] : w_hh[j * 128 + (k - 128)];
        } else if (j < 384) {
            int r = 384 + (j - 256);
            v = (k < 128) ? w_ih[r * 128 + k] : w_hh[r * 128 + (k - 128)];
        } else if (j < 512) {
            int r = 256 + (j - 384);
            v = (k < 128) ? w_ih[r * 128 + k] : 0.0f;
        } else {
            int r = 256 + (j - 512);
            v = (k < 128) ? 0.0f : w_hh[r * 128 + (k - 128)];
        }
        Wbig[i] = v;
    }
    for (size_t i = id0; i < (size_t)NW * NW; i += stride) winner[i] = -1;
}

// ---------------------------------------------------------------------------
// Tiled f32 GEMM, A given as two K-halves (A0: k<128, A1: k>=128), each with
// its own row stride.  As staged TRANSPOSED [k][row] so the inner loop reads
// a-values as one ds_read_b128 (2-way bank alias, free) instead of 4 scalar
// reads on 2 banks (8-way conflict).
// Extra blocks: first 32 do winner atomicMax (if gidx != null); all copy.
// ---------------------------------------------------------------------------
__global__ __launch_bounds__(256) void gemm_abt(
    const float* __restrict__ A0, int lda0,
    const float* __restrict__ A1, int lda1,
    const float* __restrict__ Bw, float* __restrict__ Cc, int ldc,
    int nx, int nxny,
    const int* __restrict__ gidx, int* __restrict__ winner,
    const f32x4* __restrict__ src, f32x4* __restrict__ dst, size_t lo, size_t hi) {
    __shared__ float As[32][68];     // [k][row], stride 68 (272 B, 16B-aligned)
    __shared__ float Ws[32][132];    // [k][col]
    int bid = blockIdx.x, tid = threadIdx.x;
    if (bid >= nxny) {
        int rel = bid - nxny;
        if (gidx != nullptr && rel < 32) {
            int b = rel * 256 + tid;
            int gx = gidx[2 * b] + 2, gy = gidx[2 * b + 1] + 2;
            atomicMax(&winner[gx * NW + gy], b);
        }
        size_t ctid = (size_t)rel * 256 + tid;
        copy_span(src, dst, lo, hi, ctid, (size_t)(gridDim.x - nxny) * 256);
        return;
    }
    int bx = bid % nx, by = bid / nx;
    int tn = tid & 15, tm = tid >> 4;
    size_t m0 = (size_t)bx * 64;
    int n0 = by * 128;
    float acc[4][8];
#pragma unroll
    for (int i = 0; i < 4; ++i)
#pragma unroll
        for (int j = 0; j < 8; ++j) acc[i][j] = 0.0f;

    for (int k0 = 0; k0 < KK; k0 += 32) {
        const float* a0 = (k0 < 128) ? A0 : A1;
        int lda = (k0 < 128) ? lda0 : lda1;
        int koff = k0 & 127;
        __syncthreads();
#pragma unroll
        for (int p = 0; p < 2; ++p) {        // A tile 64 rows x 32 k, transposed
            int f = tid + 256 * p; int r = f >> 3, cq = f & 7;
            float4 v = *(const float4*)(a0 + (size_t)(m0 + r) * lda + koff + 4 * cq);
            As[4 * cq + 0][r] = v.x; As[4 * cq + 1][r] = v.y;
            As[4 * cq + 2][r] = v.z; As[4 * cq + 3][r] = v.w;
        }
#pragma unroll
        for (int p = 0; p < 4; ++p) {        // B tile 128 cols x 32 k, transposed
            int f = tid + 256 * p; int c = f >> 3, cq = f & 7;
            float4 v = *(const float4*)(Bw + (size_t)(n0 + c) * KK + (k0 + 4 * cq));
            Ws[4 * cq + 0][c] = v.x; Ws[4 * cq + 1][c] = v.y;
            Ws[4 * cq + 2][c] = v.z; Ws[4 * cq + 3][c] = v.w;
        }
        __syncthreads();
#pragma unroll
        for (int kk = 0; kk < 32; ++kk) {
            float4 a4 = *(const float4*)(&As[kk][4 * tm]);
            float4 w0 = *(const float4*)(&Ws[kk][4 * tn]);
            float4 w1 = *(const float4*)(&Ws[kk][64 + 4 * tn]);
            float a_[4] = {a4.x, a4.y, a4.z, a4.w};
#pragma unroll
            for (int i = 0; i < 4; ++i) {
                acc[i][0] += a_[i] * w0.x; acc[i][1] += a_[i] * w0.y;
                acc[i][2] += a_[i] * w0.z; acc[i][3] += a_[i] * w0.w;
                acc[i][4] += a_[i] * w1.x; acc[i][5] += a_[i] * w1.y;
                acc[i][6] += a_[i] * w1.z; acc[i][7] += a_[i] * w1.w;
            }
        }
    }
#pragma unroll
    for (int i = 0; i < 4; ++i) {
        size_t row = m0 + 4 * tm + i;
        float4 v0 = make_float4(acc[i][0], acc[i][1], acc[i][2], acc[i][3]);
        float4 v1 = make_float4(acc[i][4], acc[i][5], acc[i][6], acc[i][7]);
        *(float4*)(Cc + row * ldc + n0 + 4 * tn) = v0;
        *(float4*)(Cc + row * ldc + n0 + 64 + 4 * tn) = v1;
    }
}

// ---------------------------------------------------------------------------
// Attention: one wave per b; + copy slice in extra blocks
// ---------------------------------------------------------------------------
__global__ __launch_bounds__(64) void attn_kernel(
    const float* __restrict__ C, const float* __restrict__ memory,
    const int* __restrict__ gidx, const float* __restrict__ b_ih,
    const float* __restrict__ b_hh, float* __restrict__ mixq,
    float* __restrict__ ug, float* __restrict__ sg,
    const f32x4* __restrict__ src, f32x4* __restrict__ dst, size_t lo, size_t hi) {
    int bid = blockIdx.x;
    int t = threadIdx.x;
    if (bid >= B_) {
        size_t ctid = (size_t)(bid - B_) * 64 + t;
        copy_span(src, dst, lo, hi, ctid, (size_t)(gridDim.x - B_) * 64);
        return;
    }
    int b = bid;
    int t1 = t + 64;
    const float* Crow = C + (size_t)b * NC;
    float r0 = sigmf(Crow[t]        + b_ih[t]        + b_hh[t]);
    float r1 = sigmf(Crow[t1]       + b_ih[t1]       + b_hh[t1]);
    float u0 = sigmf(Crow[128 + t]  + b_ih[128 + t]  + b_hh[128 + t]);
    float u1 = sigmf(Crow[128 + t1] + b_ih[128 + t1] + b_hh[128 + t1]);
    float s0 = sigmf(Crow[256 + t]  + b_ih[384 + t]  + b_hh[384 + t]);
    float s1 = sigmf(Crow[256 + t1] + b_ih[384 + t1] + b_hh[384 + t1]);
    float n0 = tanhf(Crow[384 + t]  + b_ih[256 + t]  + r0 * (Crow[512 + t]  + b_hh[256 + t]));
    float n1 = tanhf(Crow[384 + t1] + b_ih[256 + t1] + r1 * (Crow[512 + t1] + b_hh[256 + t1]));

    int gx = gidx[2 * b] + 2, gy = gidx[2 * b + 1] + 2;
    const float* base = memory + ((size_t)gx * NW + gy) * H_ + t;
    float cs0[25], cs1[25];
#pragma unroll
    for (int l = 0; l < 25; ++l) {
        int dx = l / 5 - 2, dy = l % 5 - 2;
        const float* row = base + ((long)dx * NW + dy) * H_;
        cs0[l] = row[0];
        cs1[l] = row[64];
    }
    float sc[25];
#pragma unroll
    for (int l = 0; l < 25; ++l) {
        float p = n0 * cs0[l] + n1 * cs1[l];
#pragma unroll
        for (int w = 1; w < 64; w <<= 1) p += __shfl_xor(p, w, 64);
        sc[l] = p;
    }
    float mx = sc[0];
#pragma unroll
    for (int l = 1; l < 25; ++l) mx = fmaxf(mx, sc[l]);
    float den = 0.0f, mix0 = 0.0f, mix1 = 0.0f;
#pragma unroll
    for (int l = 0; l < 25; ++l) {
        float e = expf(sc[l] - mx);
        den += e;
        mix0 += e * cs0[l];
        mix1 += e * cs1[l];
    }
    float inv = 1.0f / den;
    mix0 *= inv; mix1 *= inv;

    float* mq = mixq + (size_t)b * 256;
    mq[t] = mix0; mq[t1] = mix1; mq[128 + t] = n0; mq[128 + t1] = n1;
    ug[(size_t)b * H_ + t] = u0; ug[(size_t)b * H_ + t1] = u1;
    sg[(size_t)b * H_ + t] = s0; sg[(size_t)b * H_ + t1] = s1;
}

// ---------------------------------------------------------------------------
// Pure bulk copy (serial-fallback path only)
// ---------------------------------------------------------------------------
__global__ void copy_kernel(const f32x4* __restrict__ src, f32x4* __restrict__ dst, size_t n4) {
    size_t stride = (size_t)gridDim.x * blockDim.x;
    for (size_t i = (size_t)blockIdx.x * blockDim.x + threadIdx.x; i < n4; i += stride) {
        f32x4 v = __builtin_nontemporal_load(src + i);
        __builtin_nontemporal_store(v, dst + i);
    }
}

// ---------------------------------------------------------------------------
// Final: hyy + scatter winner rows into newmem; copy slice skipping winner cells
// ---------------------------------------------------------------------------
__global__ __launch_bounds__(256) void final_kernel(
    const float* __restrict__ AC, const float* __restrict__ b_out,
    const float* __restrict__ sg, const float* __restrict__ ug,
    const float* __restrict__ mixq, const float* __restrict__ hx,
    const float* __restrict__ memory, const int* __restrict__ gidx,
    const int* __restrict__ winner, float* __restrict__ hyy,
    float* __restrict__ newmem,
    const f32x4* __restrict__ src, f32x4* __restrict__ dst, size_t lo, size_t hi) {
    size_t gt = (size_t)blockIdx.x * blockDim.x + threadIdx.x;
    size_t nthr = (size_t)gridDim.x * blockDim.x;
    for (size_t i = gt; i < (size_t)B_ * H_; i += nthr) {
        int b = (int)(i >> 7), t = (int)(i & 127);
        float atten = tanhf(AC[i] + b_out[t]);
        float s = sg[i], u = ug[i];
        float q = mixq[(size_t)b * 256 + 128 + t];
        float curr = q + s * atten;
        float hy = curr + u * (hx[i] - curr);
        hyy[i] = hy;
        int gx = gidx[2 * b] + 2, gy = gidx[2 * b + 1] + 2;
        size_t cell = (size_t)gx * NW + gy;
        if (winner[cell] == b) {
            float m = memory[cell * H_ + t];
            newmem[cell * H_ + t] = s * m + (1.0f - s) * hy;
        }
    }
    // copy slice, skipping cells owned by the scatter (written above)
    for (size_t i = lo + gt; i < hi; i += nthr) {
        if (winner[i >> 5] < 0) {
            f32x4 v = __builtin_nontemporal_load(src + i);
            __builtin_nontemporal_store(v, dst + i);
        }
    }
}

extern "C" void kernel_launch(void* const* d_in, const int* in_sizes, int n_in,
                              void* d_out, int out_size, void* d_ws, size_t ws_size,
                              hipStream_t stream) {
    const float* xf     = (const float*)d_in[0];
    const float* hx     = (const float*)d_in[1];
    const int*   gidx   = (const int*)d_in[2];
    const float* memory = (const float*)d_in[3];
    const float* w_ih   = (const float*)d_in[4];
    const float* w_hh   = (const float*)d_in[5];
    const float* b_ih   = (const float*)d_in[6];
    const float* b_hh   = (const float*)d_in[7];
    const float* w_out  = (const float*)d_in[8];
    const float* b_out  = (const float*)d_in[9];

    float* out    = (float*)d_out;
    float* hyy    = out;
    float* newmem = out + (size_t)B_ * H_;
    const f32x4* src4 = (const f32x4*)memory;
    f32x4*       dst4 = (f32x4*)newmem;

    // Persistent scratch: mixq, ug, sg, AC, winner
    float* wsf    = (float*)d_ws;
    float* mixq   = wsf;                           // B*256
    float* ug     = mixq + (size_t)B_ * 256;       // B*128
    float* sg     = ug + (size_t)B_ * H_;          // B*128
    float* AC     = sg + (size_t)B_ * H_;          // B*128
    int*   winner = (int*)(AC + (size_t)B_ * H_);  // NW*NW ints
    char*  pers_end = (char*)(winner + (size_t)NW * NW);
    size_t pers_bytes = (size_t)(pers_end - (char*)d_ws);

    size_t CF = (size_t)B_ * NC, WBF = (size_t)NC * 256;
    size_t trans_bytes = (CF + WBF) * sizeof(float);
    bool distributed = (ws_size >= pers_bytes + trans_bytes);
    float* trans = distributed ? (float*)pers_end : newmem;
    float* Cbuf = trans;
    float* Wbig = Cbuf + CF;

    if (distributed) {
        size_t a1 = SL_A, b1 = a1 + SL_B, c1 = b1 + SL_C, d1 = c1 + SL_D;
        prep_kernel<<<PREP_CB + PREP_CPB, 256, 0, stream>>>(
            w_ih, w_hh, Wbig, winner, src4, dst4, 0, a1);
        gemm_abt<<<640 + GEMM_CPB, 256, 0, stream>>>(
            xf, 128, hx, 128, Wbig, Cbuf, NC, 128, 640, gidx, winner,
            src4, dst4, a1, b1);
        attn_kernel<<<B_ + ATTN_CPB, 64, 0, stream>>>(
            Cbuf, memory, gidx, b_ih, b_hh, mixq, ug, sg, src4, dst4, b1, c1);
        gemm_abt<<<128 + GEMM_CPB, 256, 0, stream>>>(
            mixq, 256, mixq + 128, 256, w_out, AC, H_, 128, 128, nullptr, winner,
            src4, dst4, c1, d1);
        final_kernel<<<FIN_BLKS, 256, 0, stream>>>(
            AC, b_out, sg, ug, mixq, hx, memory, gidx, winner, hyy, newmem,
            src4, dst4, d1, N4TOT);
    } else {
        // serial fallback: transients staged in not-yet-copied newmem region
        prep_kernel<<<PREP_CB, 256, 0, stream>>>(
            w_ih, w_hh, Wbig, winner, src4, dst4, 0, 0);
        gemm_abt<<<640 + 32, 256, 0, stream>>>(
            xf, 128, hx, 128, Wbig, Cbuf, NC, 128, 640, gidx, winner,
            src4, dst4, 0, 0);
        attn_kernel<<<B_, 64, 0, stream>>>(
            Cbuf, memory, gidx, b_ih, b_hh, mixq, ug, sg, src4, dst4, 0, 0);
        gemm_abt<<<128, 256, 0, stream>>>(
            mixq, 256, mixq + 128, 256, w_out, AC, H_, 128, 128, nullptr, winner,
            src4, dst4, 0, 0);
        copy_kernel<<<2048, 256, 0, stream>>>(src4, dst4, N4TOT);
        final_kernel<<<FIN_BLKS, 256, 0, stream>>>(
            AC, b_out, sg, ug, mixq, hx, memory, gidx, winner, hyy, newmem,
            src4, dst4, 0, 0);
    }
}